// Round 10
// baseline (4790.868 us; speedup 1.0000x reference)
//
#include <hip/hip_runtime.h>
#include <hip/hip_bf16.h>

#define N_PTS 16384
#define KNN   20
#define LIST  32   // approx-stage list width per candidate-eighth (refine is exact)
#define NSPLIT 8   // candidate-range split

typedef __attribute__((ext_vector_type(8))) short bf16x8;
typedef __attribute__((ext_vector_type(4))) float f32x4;

// Load B fragments (16 candidate rows x 32k-chunk) for one tile, direct
// global -> registers. Row = c0 + (ln&15), chunk = kc*4 + (ln>>4).
template<int F>
__device__ __forceinline__ void load_B(const ushort* __restrict__ Xh,
                                       const ushort* __restrict__ Xl,
                                       const float* __restrict__ sqn,
                                       int c0, int ln,
                                       bf16x8 (&bh)[F / 32], bf16x8 (&bl)[F / 32],
                                       float& cn) {
  constexpr int KC = F / 32;
  const int apc = ln >> 4;
  size_t roff = (size_t)(c0 + (ln & 15)) * F;
#pragma unroll
  for (int kc = 0; kc < KC; ++kc) {
    size_t off = roff + (size_t)(kc * 4 + apc) * 8;
    bh[kc] = *(const bf16x8*)(Xh + off);
    bl[kc] = *(const bf16x8*)(Xl + off);
  }
  cn = sqn[c0 + (ln & 15)];
}

// Fused bf16x3-MFMA distance + buffered top-32 kNN over an EIGHTH of the
// candidate range. ONE wave per block, 32 queries per wave (two 16-row A
// groups sharing every B fragment). Candidates stream global->reg (L2
// resident, no barriers). Selection: shfl-free parallel appends (per-lane
// replicated group counts) + rare wave-collective bitonic merges.
template<int F>
__global__ __launch_bounds__(64, 4) void knn_kernel(const ushort* __restrict__ Xh,
                                                    const ushort* __restrict__ Xl,
                                                    const float* __restrict__ sqn,
                                                    int* __restrict__ out_cand) {
  constexpr int KC = F / 32;            // 32-k chunks per row
  constexpr int NC = N_PTS / NSPLIT;    // candidates per block
  constexpr int TS = 16;                // candidate tile (one MFMA column tile)
  constexpr int NT = NC / TS;
  __shared__ float  Bs[32 * LIST];      // survivor scores
  __shared__ ushort Bi[32 * LIST];      // survivor indices
  __shared__ float  Ld[32 * LIST];      // sorted distances
  __shared__ ushort Li[32 * LIST];      // sorted indices

  const int ln = threadIdx.x;
  const int q0 = (int)(blockIdx.x >> 3) * 32;
  const int hf = blockIdx.x & 7;
  const int cbase = hf * NC;

  // init sorted lists (32 queries x 32 entries)
#pragma unroll
  for (int k = 0; k < 16; ++k) {
    int idx = k * 64 + ln;
    Ld[idx] = 3.0e38f; Li[idx] = 0;
  }
  float thr_reg = 3.0e38f;   // lane j<32: 32nd-best of query j
  float myth[8];             // own-score thresholds per (qg,r) group
  int   cnt8[8];             // per-lane replicated buffered-count of my slot's query
#pragma unroll
  for (int i = 0; i < 8; ++i) { myth[i] = 3.0e38f; cnt8[i] = 0; }
  int bcnt = 0;              // lane j<32: buffered count of query j (merge bookkeeping)

  // wave-collective merge of query qk's buffer into its sorted top-32
  auto merge_q = [&](int qk) {
    int cnt = __shfl(bcnt, qk);
    int lrow = qk * LIST;
    float key; int id;
    if (ln < 32) { key = Ld[lrow + ln]; id = (int)Li[lrow + ln]; }
    else {
      int j = ln - 32;
      bool v = j < cnt;
      key = v ? Bs[lrow + j] : 3.0e38f;
      id  = v ? (int)Bi[lrow + j] : 65535;
    }
#pragma unroll
    for (int kk = 2; kk <= 64; kk <<= 1) {
#pragma unroll
      for (int jj = kk >> 1; jj > 0; jj >>= 1) {
        float ok = __shfl_xor(key, jj);
        int   oi = __shfl_xor(id, jj);
        bool pless = (ok < key) || (ok == key && oi < id);
        bool take = pless == (((ln & jj) == 0) == ((ln & kk) == 0));
        key = take ? ok : key;
        id  = take ? oi : id;
      }
    }
    if (ln < 32) { Ld[lrow + ln] = key; Li[lrow + ln] = (ushort)id; }
    float tnew = __shfl(key, 31);
    thr_reg = (ln == qk) ? tnew : thr_reg;
    bcnt    = (ln == qk) ? 0 : bcnt;
    // reset the per-lane replicated count for the merged query
    int slot = (qk >> 2) & 3;
    int g = ((qk >> 4) << 2) + (qk & 3);
#pragma unroll
    for (int i = 0; i < 8; ++i)
      if (i == g && (ln >> 4) == slot) cnt8[i] = 0;
  };

  // A fragments: 2 query groups x KC chunks, hi/lo — direct from global
  bf16x8 ah[2][KC], al[2][KC];
  {
    const int apc = ln >> 4;
#pragma unroll
    for (int qg = 0; qg < 2; ++qg)
#pragma unroll
      for (int kc = 0; kc < KC; ++kc) {
        size_t off = (size_t)(q0 + qg * 16 + (ln & 15)) * F + (size_t)(kc * 4 + apc) * 8;
        ah[qg][kc] = *(const bf16x8*)(Xh + off);
        al[qg][kc] = *(const bf16x8*)(Xl + off);
      }
  }

  // register double-buffered B tiles (named sets — no runtime indexing)
  bf16x8 b0h[KC], b0l[KC], b1h[KC], b1l[KC];
  float cn0, cn1;
  load_B<F>(Xh, Xl, sqn, cbase, ln, b0h, b0l, cn0);
  load_B<F>(Xh, Xl, sqn, cbase + TS, ln, b1h, b1l, cn1);

  const unsigned long long gmask = 0xFFFFull << (ln & 48);
  const unsigned long long below = (1ull << ln) - 1;

  // one pipeline step: MFMA(tile t) -> scores -> reload(t+2) -> selection
  auto step = [&](bf16x8 (&bh)[KC], bf16x8 (&bl)[KC], float& cn, int t) {
    f32x4 aH[2], aX[2];
#pragma unroll
    for (int qg = 0; qg < 2; ++qg) { aH[qg] = (f32x4){0,0,0,0}; aX[qg] = (f32x4){0,0,0,0}; }
    __builtin_amdgcn_s_setprio(1);
#pragma unroll
    for (int kc = 0; kc < KC; ++kc) {
#pragma unroll
      for (int qg = 0; qg < 2; ++qg) {
        aH[qg] = __builtin_amdgcn_mfma_f32_16x16x32_bf16(ah[qg][kc], bh[kc], aH[qg], 0, 0, 0);
        aX[qg] = __builtin_amdgcn_mfma_f32_16x16x32_bf16(al[qg][kc], bh[kc], aX[qg], 0, 0, 0);
        aX[qg] = __builtin_amdgcn_mfma_f32_16x16x32_bf16(ah[qg][kc], bl[kc], aX[qg], 0, 0, 0);
      }
    }
    __builtin_amdgcn_s_setprio(0);
    // scores: query qg*16+(ln>>4)*4+r, cand t*TS+(ln&15)
    float s8[8];
#pragma unroll
    for (int qg = 0; qg < 2; ++qg)
#pragma unroll
      for (int r = 0; r < 4; ++r)
        s8[qg * 4 + r] = cn - 2.0f * (aH[qg][r] + aX[qg][r]);

    // reload this register set for tile t+2 (latency hidden under next step)
    if (t + 2 < NT) load_B<F>(Xh, Xl, sqn, cbase + (t + 2) * TS, ln, bh, bl, cn);

    // selection: 8 independent ballot groups, shfl-free appends
    const int ci = cbase + t * TS + (ln & 15);
#pragma unroll
    for (int qg = 0; qg < 2; ++qg)
#pragma unroll
      for (int r = 0; r < 4; ++r) {
        const int g = qg * 4 + r;
        float s = s8[g];
        unsigned long long m = __ballot(s < myth[g]);
        if (m) {
          if (s < myth[g]) {
            int qk = qg * 16 + ((ln & 48) >> 2) + r;
            int pos = cnt8[g] + __popcll(m & gmask & below);
            Bs[qk * LIST + pos] = s;
            Bi[qk * LIST + pos] = (ushort)ci;
          }
          cnt8[g] += __popcll(m & gmask);
          if (ln < 32 && (ln >> 4) == qg && (ln & 3) == r)
            bcnt += __popcll((m >> (((ln & 15) >> 2) * 16)) & 0xFFFFull);
        }
      }
    // overflow merges once per step: per-query appends/step <= 16, cap 32
    unsigned long long mm = __ballot(ln < 32 && bcnt > 16);
    if (mm) {
      do {
        int qk = __ffsll(mm) - 1;
        mm &= mm - 1;
        merge_q(qk);
      } while (mm);
#pragma unroll
      for (int qg = 0; qg < 2; ++qg)
#pragma unroll
        for (int r = 0; r < 4; ++r)
          myth[qg * 4 + r] = __shfl(thr_reg, qg * 16 + ((ln & 48) >> 2) + r);
    }
  };

#pragma unroll 1
  for (int t = 0; t < NT; t += 2) {
    step(b0h, b0l, cn0, t);
    step(b1h, b1l, cn1, t + 1);
  }

  // final flush
  {
    unsigned long long mm = __ballot(ln < 32 && bcnt > 0);
    while (mm) {
      int qk = __ffsll(mm) - 1;
      mm &= mm - 1;
      merge_q(qk);
    }
  }

  // write 32 queries x 32 candidates
#pragma unroll
  for (int k2 = 0; k2 < 16; ++k2) {
    int row = k2 * 2 + (ln >> 5);
    int col = ln & 31;
    out_cand[(size_t)(q0 + row) * (NSPLIT * LIST) + hf * LIST + col] = (int)Li[row * LIST + col];
  }
}

// Exact fp32 re-rank of the 256 union candidates -> true fp32 top-20 set.
// One wave per query; lane l handles candidates l, l+64, l+128, l+192.
template<int F>
__global__ __launch_bounds__(256) void refine_kernel(const float* __restrict__ X,
                                                     const float* __restrict__ sqn,
                                                     const int* __restrict__ cand,
                                                     int* __restrict__ out_idx) {
  constexpr int CW = NSPLIT * LIST;  // 256
  const int wv = threadIdx.x >> 6, ln = threadIdx.x & 63;
  const int q = blockIdx.x * 4 + wv;
  int c[4]; float s[4];
#pragma unroll
  for (int i = 0; i < 4; ++i) c[i] = cand[(size_t)q * CW + i * 64 + ln];
  const float* qrow = X + (size_t)q * F;
#pragma unroll
  for (int i = 0; i < 4; ++i) {
    const float* crow = X + (size_t)c[i] * F;
    float dot = 0.f;
#pragma unroll
    for (int d = 0; d < F; d += 4) {
      float4 qv = *(const float4*)(qrow + d);
      float4 cv = *(const float4*)(crow + d);
      dot += qv.x * cv.x + qv.y * cv.y + qv.z * cv.z + qv.w * cv.w;
    }
    s[i] = sqn[c[i]] - 2.0f * dot;
  }
  // rank by (score asc, index asc); eighths are disjoint -> no duplicates
  int rank[4] = {0, 0, 0, 0};
#pragma unroll 1
  for (int j = 0; j < 64; ++j) {
#pragma unroll
    for (int a = 0; a < 4; ++a) {
      float sa = __shfl(s[a], j);
      int   ca = __shfl(c[a], j);
#pragma unroll
      for (int b = 0; b < 4; ++b)
        rank[b] += (sa < s[b]) || (sa == s[b] && ca < c[b]);
    }
  }
#pragma unroll
  for (int i = 0; i < 4; ++i)
    if (rank[i] < KNN) out_idx[(size_t)q * KNN + rank[i]] = c[i];
}

// x1 = relu(pos @ W1 + b1) + bf16 hi/lo split + squared row norms.
__global__ __launch_bounds__(256) void mlp1_kernel(const float* __restrict__ pos,
                                                   const float* __restrict__ W1,
                                                   const float* __restrict__ b1,
                                                   float* __restrict__ x1,
                                                   ushort* __restrict__ xh,
                                                   ushort* __restrict__ xl,
                                                   float* __restrict__ sqn) {
  int i = blockIdx.x * 4 + (threadIdx.x >> 6);
  int o = threadIdx.x & 63;
  float p0 = pos[i * 3], p1 = pos[i * 3 + 1], p2 = pos[i * 3 + 2];
  float v = p0 * W1[o] + p1 * W1[64 + o] + p2 * W1[128 + o] + b1[o];
  v = fmaxf(v, 0.f);
  x1[(size_t)i * 64 + o] = v;
  __hip_bfloat16 h = __float2bfloat16(v);
  float hv = __bfloat162float(h);
  __hip_bfloat16 l2 = __float2bfloat16(v - hv);
  xh[(size_t)i * 64 + o] = *(ushort*)&h;
  xl[(size_t)i * 64 + o] = *(ushort*)&l2;
  float ss = v * v;
#pragma unroll
  for (int d = 32; d; d >>= 1) ss += __shfl_xor(ss, d);
  if (o == 0) sqn[i] = ss;
}

// Fused P = X@Wp + bias, Q = X@Wq (shared X staging). 4 rows x float4 each.
template<int K, int OUT>
__global__ __launch_bounds__(256) void linpq_kernel(const float* __restrict__ X,
                                                    const float* __restrict__ Wp,
                                                    const float* __restrict__ bp,
                                                    const float* __restrict__ Wq,
                                                    float* __restrict__ P,
                                                    float* __restrict__ Q) {
  constexpr int XD = OUT / 4;
  constexpr int YD = 256 / XD;
  constexpr int R = YD * 4;
  __shared__ float xs[R * K];
  const int tid = threadIdx.x;
  const int tx = tid % XD, ty = tid / XD;
  const size_t r0 = (size_t)blockIdx.x * R;
  const float4* Xv = (const float4*)(X + r0 * K);
  float4* xsv = (float4*)xs;
#pragma unroll
  for (int i2 = tid; i2 < R * K / 4; i2 += 256) xsv[i2] = Xv[i2];
  __syncthreads();
  float4 ap[4], aq[4];
#pragma unroll
  for (int i = 0; i < 4; i++) { ap[i] = make_float4(0,0,0,0); aq[i] = make_float4(0,0,0,0); }
  const float4* Wp4 = (const float4*)Wp;
  const float4* Wq4 = (const float4*)Wq;
#pragma unroll 4
  for (int k = 0; k < K; ++k) {
    float4 wp = Wp4[k * XD + tx];
    float4 wq = Wq4[k * XD + tx];
#pragma unroll
    for (int i = 0; i < 4; i++) {
      float xv = xs[(ty * 4 + i) * K + k];
      ap[i].x += xv * wp.x; ap[i].y += xv * wp.y; ap[i].z += xv * wp.z; ap[i].w += xv * wp.w;
      aq[i].x += xv * wq.x; aq[i].y += xv * wq.y; aq[i].z += xv * wq.z; aq[i].w += xv * wq.w;
    }
  }
  float4 bv = ((const float4*)bp)[tx];
#pragma unroll
  for (int i = 0; i < 4; i++) {
    float4 o;
    o.x = ap[i].x + bv.x; o.y = ap[i].y + bv.y; o.z = ap[i].z + bv.z; o.w = ap[i].w + bv.w;
    ((float4*)(P + (r0 + ty * 4 + i) * OUT))[tx] = o;
    ((float4*)(Q + (r0 + ty * 4 + i) * OUT))[tx] = aq[i];
  }
}

// Layer-1 epilogue fused: x2 = relu(P + max_j Q[nb]), plus hi/lo split + norms.
__global__ void maxpoolprep_kernel(const float* __restrict__ P, const float* __restrict__ Qm,
                                   const int* __restrict__ idx, float* __restrict__ xo,
                                   ushort* __restrict__ xh, ushort* __restrict__ xl,
                                   float* __restrict__ sqn) {
  __shared__ int nb[KNN];
  __shared__ float part[2];
  int i = blockIdx.x;
  if (threadIdx.x < KNN) nb[threadIdx.x] = idx[(size_t)i * KNN + threadIdx.x];
  __syncthreads();
  int o = threadIdx.x;  // 128 threads
  float m = -3.0e38f;
#pragma unroll
  for (int j = 0; j < KNN; j++) m = fmaxf(m, Qm[(size_t)nb[j] * 128 + o]);
  float v = fmaxf(P[(size_t)i * 128 + o] + m, 0.f);
  xo[(size_t)i * 128 + o] = v;
  __hip_bfloat16 h = __float2bfloat16(v);
  float hv = __bfloat162float(h);
  __hip_bfloat16 l2 = __float2bfloat16(v - hv);
  xh[(size_t)i * 128 + o] = *(ushort*)&h;
  xl[(size_t)i * 128 + o] = *(ushort*)&l2;
  float ss = v * v;
#pragma unroll
  for (int d = 32; d; d >>= 1) ss += __shfl_xor(ss, d);
  if ((threadIdx.x & 63) == 0) part[threadIdx.x >> 6] = ss;
  __syncthreads();
  if (threadIdx.x == 0) sqn[i] = part[0] + part[1];
}

// out_i = relu(P_i + max_j Q[idx[i][j]])
template<int OUT>
__global__ void maxpool_kernel(const float* __restrict__ P, const float* __restrict__ Q,
                               const int* __restrict__ idx, float* __restrict__ xo) {
  __shared__ int nb[KNN];
  int i = blockIdx.x;
  if (threadIdx.x < KNN) nb[threadIdx.x] = idx[(size_t)i * KNN + threadIdx.x];
  __syncthreads();
  int o = threadIdx.x;
  float m = -3.0e38f;
#pragma unroll
  for (int j = 0; j < KNN; j++) m = fmaxf(m, Q[(size_t)nb[j] * OUT + o]);
  float p = P[(size_t)i * OUT + o];
  xo[(size_t)i * OUT + o] = fmaxf(p + m, 0.f);
}

// C[N x OUT] = X[N x K] @ W[K x OUT] (+ bias). Register-tiled 4 rows x float4.
template<int K, int OUT, bool BIAS>
__global__ __launch_bounds__(256) void lin_kernel(const float* __restrict__ X,
                                                  const float* __restrict__ W,
                                                  const float* __restrict__ bias,
                                                  float* __restrict__ C) {
  constexpr int XD = OUT / 4;
  constexpr int YD = 256 / XD;
  constexpr int R = YD * 4;
  __shared__ float xs[R * K];
  const int tid = threadIdx.x;
  const int tx = tid % XD, ty = tid / XD;
  const size_t r0 = (size_t)blockIdx.x * R;
  const float4* Xv = (const float4*)(X + r0 * K);
  float4* xsv = (float4*)xs;
#pragma unroll
  for (int i2 = tid; i2 < R * K / 4; i2 += 256) xsv[i2] = Xv[i2];
  __syncthreads();
  float4 acc[4];
#pragma unroll
  for (int i = 0; i < 4; i++) acc[i] = make_float4(0.f, 0.f, 0.f, 0.f);
  const float4* W4 = (const float4*)W;
#pragma unroll 8
  for (int k = 0; k < K; ++k) {
    float4 wv = W4[k * XD + tx];
#pragma unroll
    for (int i = 0; i < 4; i++) {
      float xv = xs[(ty * 4 + i) * K + k];
      acc[i].x += xv * wv.x; acc[i].y += xv * wv.y;
      acc[i].z += xv * wv.z; acc[i].w += xv * wv.w;
    }
  }
  float4 bv = make_float4(0.f, 0.f, 0.f, 0.f);
  if (BIAS) bv = ((const float4*)bias)[tx];
#pragma unroll
  for (int i = 0; i < 4; i++) {
    float4 o;
    o.x = acc[i].x + bv.x; o.y = acc[i].y + bv.y;
    o.z = acc[i].z + bv.z; o.w = acc[i].w + bv.w;
    ((float4*)(C + (r0 + ty * 4 + i) * OUT))[tx] = o;
  }
}

// Wp[k][o] = We[k][o] - We[K+k][o]
__global__ void wsub_kernel(const float* __restrict__ We, float* __restrict__ Wp, int total) {
  int t = blockIdx.x * 256 + threadIdx.x;
  if (t < total) Wp[t] = We[t] - We[total + t];
}

extern "C" void kernel_launch(void* const* d_in, const int* in_sizes, int n_in,
                              void* d_out, int out_size, void* d_ws, size_t ws_size,
                              hipStream_t stream) {
  const float* pos = (const float*)d_in[0];
  const float* W1  = (const float*)d_in[1];
  const float* b1  = (const float*)d_in[2];
  const float* We1 = (const float*)d_in[3];
  const float* be1 = (const float*)d_in[4];
  const float* We2 = (const float*)d_in[5];
  const float* be2 = (const float*)d_in[6];
  const float* W2  = (const float*)d_in[7];
  const float* b2  = (const float*)d_in[8];
  float* out = (float*)d_out;

  const size_t N = N_PTS;
  float* ws  = (float*)d_ws;
  float* x1  = ws;               // N*64
  float* P1  = x1 + N * 64;      // N*128
  float* Q1  = P1 + N * 128;     // N*128
  float* x2  = Q1 + N * 128;     // N*128
  float* P2  = x2 + N * 128;     // N*256
  float* Q2  = P2 + N * 256;     // N*256
  float* x3  = Q2 + N * 256;     // N*256
  float* sqn = x3 + N * 256;     // N (x1 norms, then x2 norms)
  float* Wp1 = sqn + N;          // 64*128
  float* Wp2 = Wp1 + 64 * 128;   // 128*256
  int* idx1  = (int*)(Wp2 + 128 * 256);  // N*20
  int* idx2  = idx1 + N * KNN;           // N*20
  // cand aliases Q2's slot (N*256 ints == N*256 floats): fully consumed by
  // refine before Q2 is written by linpq (same stream, program order).
  int* cand  = (int*)Q2;
  ushort* X1h = (ushort*)(idx2 + N * KNN);  // N*64
  ushort* X1l = X1h + N * 64;               // N*64
  ushort* X2h = X1l + N * 64;               // N*128
  ushort* X2l = X2h + N * 128;              // N*128
  size_t need = (size_t)((char*)(X2l + N * 128) - (char*)d_ws);
  if (ws_size < need) return;  // insufficient scratch -> visible failure

  wsub_kernel<<<(64 * 128 + 255) / 256, 256, 0, stream>>>(We1, Wp1, 64 * 128);
  wsub_kernel<<<(128 * 256 + 255) / 256, 256, 0, stream>>>(We2, Wp2, 128 * 256);

  mlp1_kernel<<<N / 4, 256, 0, stream>>>(pos, W1, b1, x1, X1h, X1l, sqn);
  knn_kernel<64><<<(N / 32) * NSPLIT, 64, 0, stream>>>(X1h, X1l, sqn, cand);   // 4096 blocks
  refine_kernel<64><<<N / 4, 256, 0, stream>>>(x1, sqn, cand, idx1);
  linpq_kernel<64, 128><<<N / 32, 256, 0, stream>>>(x1, Wp1, be1, We1 + 64 * 128, P1, Q1);
  maxpoolprep_kernel<<<N, 128, 0, stream>>>(P1, Q1, idx1, x2, X2h, X2l, sqn);

  knn_kernel<128><<<(N / 32) * NSPLIT, 64, 0, stream>>>(X2h, X2l, sqn, cand);  // 4096 blocks
  refine_kernel<128><<<N / 4, 256, 0, stream>>>(x2, sqn, cand, idx2);
  linpq_kernel<128, 256><<<N / 16, 256, 0, stream>>>(x2, Wp2, be2, We2 + 128 * 256, P2, Q2);
  maxpool_kernel<256><<<N, 256, 0, stream>>>(P2, Q2, idx2, x3);

  lin_kernel<256, 128, true ><<<N / 32, 256, 0, stream>>>(x3, W2, b2, out);
}

// Round 11
// 3683.404 us; speedup vs baseline: 1.3007x; 1.3007x over previous
//
#include <hip/hip_runtime.h>
#include <hip/hip_bf16.h>

#define N_PTS 16384
#define KNN   20
#define LIST  32   // approx-stage list width per candidate-eighth (refine is exact)
#define NSPLIT 8   // candidate-range split (aligned with 8 XCDs via bid&7)

typedef __attribute__((ext_vector_type(8))) short bf16x8;
typedef __attribute__((ext_vector_type(4))) float f32x4;

// Load B fragments (16 candidate rows x 32k-chunk) for one tile, direct
// global -> registers. Row = c0 + (ln&15), chunk = kc*4 + (ln>>4).
template<int F>
__device__ __forceinline__ void load_B(const ushort* __restrict__ Xh,
                                       const ushort* __restrict__ Xl,
                                       const float* __restrict__ sqn,
                                       int c0, int ln,
                                       bf16x8 (&bh)[F / 32], bf16x8 (&bl)[F / 32],
                                       float& cn) {
  constexpr int KC = F / 32;
  const int apc = ln >> 4;
  size_t roff = (size_t)(c0 + (ln & 15)) * F;
#pragma unroll
  for (int kc = 0; kc < KC; ++kc) {
    size_t off = roff + (size_t)(kc * 4 + apc) * 8;
    bh[kc] = *(const bf16x8*)(Xh + off);
    bl[kc] = *(const bf16x8*)(Xl + off);
  }
  cn = sqn[c0 + (ln & 15)];
}

// Fused bf16x3-MFMA distance + buffered top-32 kNN over an EIGHTH of the
// candidate range. ONE wave per block, 32 queries per wave. Candidates
// stream global->reg (per-XCD L2-resident slice; no barriers). Selection:
// shfl-free parallel appends + rare wave-collective bitonic merges.
// NOTE: __launch_bounds__(64,2) — (64,4) forces VGPR<=128 and SPILLS
// (round-10: WRITE_SIZE 8MB->1.9GB, 2.7x slower). Do not tighten.
template<int F>
__global__ __launch_bounds__(64, 2) void knn_kernel(const ushort* __restrict__ Xh,
                                                    const ushort* __restrict__ Xl,
                                                    const float* __restrict__ sqn,
                                                    int* __restrict__ out_cand) {
  constexpr int KC = F / 32;            // 32-k chunks per row
  constexpr int NC = N_PTS / NSPLIT;    // candidates per block
  constexpr int TS = 16;                // candidate tile (one MFMA column tile)
  constexpr int NT = NC / TS;
  __shared__ float  Bs[32 * LIST];      // survivor scores
  __shared__ ushort Bi[32 * LIST];      // survivor indices
  __shared__ float  Ld[32 * LIST];      // sorted distances
  __shared__ ushort Li[32 * LIST];      // sorted indices

  const int ln = threadIdx.x;
  const int q0 = (int)(blockIdx.x >> 3) * 32;
  const int hf = blockIdx.x & 7;        // = XCD id under round-robin dispatch
  const int cbase = hf * NC;

  // init sorted lists (32 queries x 32 entries)
#pragma unroll
  for (int k = 0; k < 16; ++k) {
    int idx = k * 64 + ln;
    Ld[idx] = 3.0e38f; Li[idx] = 0;
  }
  float thr_reg = 3.0e38f;   // lane j<32: 32nd-best of query j
  float myth[8];             // own-score thresholds per (qg,r) group
  int   cnt8[8];             // per-lane replicated buffered-count of my slot's query
#pragma unroll
  for (int i = 0; i < 8; ++i) { myth[i] = 3.0e38f; cnt8[i] = 0; }
  int bcnt = 0;              // lane j<32: buffered count of query j (merge bookkeeping)

  // wave-collective merge of query qk's buffer into its sorted top-32
  auto merge_q = [&](int qk) {
    int cnt = __shfl(bcnt, qk);
    int lrow = qk * LIST;
    float key; int id;
    if (ln < 32) { key = Ld[lrow + ln]; id = (int)Li[lrow + ln]; }
    else {
      int j = ln - 32;
      bool v = j < cnt;
      key = v ? Bs[lrow + j] : 3.0e38f;
      id  = v ? (int)Bi[lrow + j] : 65535;
    }
#pragma unroll
    for (int kk = 2; kk <= 64; kk <<= 1) {
#pragma unroll
      for (int jj = kk >> 1; jj > 0; jj >>= 1) {
        float ok = __shfl_xor(key, jj);
        int   oi = __shfl_xor(id, jj);
        bool pless = (ok < key) || (ok == key && oi < id);
        bool take = pless == (((ln & jj) == 0) == ((ln & kk) == 0));
        key = take ? ok : key;
        id  = take ? oi : id;
      }
    }
    if (ln < 32) { Ld[lrow + ln] = key; Li[lrow + ln] = (ushort)id; }
    float tnew = __shfl(key, 31);
    thr_reg = (ln == qk) ? tnew : thr_reg;
    bcnt    = (ln == qk) ? 0 : bcnt;
    // reset the per-lane replicated count for the merged query
    int slot = (qk >> 2) & 3;
    int g = ((qk >> 4) << 2) + (qk & 3);
#pragma unroll
    for (int i = 0; i < 8; ++i)
      if (i == g && (ln >> 4) == slot) cnt8[i] = 0;
  };

  // A fragments: 2 query groups x KC chunks, hi/lo — direct from global
  bf16x8 ah[2][KC], al[2][KC];
  {
    const int apc = ln >> 4;
#pragma unroll
    for (int qg = 0; qg < 2; ++qg)
#pragma unroll
      for (int kc = 0; kc < KC; ++kc) {
        size_t off = (size_t)(q0 + qg * 16 + (ln & 15)) * F + (size_t)(kc * 4 + apc) * 8;
        ah[qg][kc] = *(const bf16x8*)(Xh + off);
        al[qg][kc] = *(const bf16x8*)(Xl + off);
      }
  }

  // register double-buffered B tiles (named sets — no runtime indexing)
  bf16x8 b0h[KC], b0l[KC], b1h[KC], b1l[KC];
  float cn0, cn1;
  load_B<F>(Xh, Xl, sqn, cbase, ln, b0h, b0l, cn0);
  load_B<F>(Xh, Xl, sqn, cbase + TS, ln, b1h, b1l, cn1);

  const unsigned long long gmask = 0xFFFFull << (ln & 48);
  const unsigned long long below = (1ull << ln) - 1;

  // one pipeline step: MFMA(tile t) -> scores -> reload(t+2) -> selection
  auto step = [&](bf16x8 (&bh)[KC], bf16x8 (&bl)[KC], float& cn, int t) {
    f32x4 aH[2], aX[2];
#pragma unroll
    for (int qg = 0; qg < 2; ++qg) { aH[qg] = (f32x4){0,0,0,0}; aX[qg] = (f32x4){0,0,0,0}; }
    __builtin_amdgcn_s_setprio(1);
#pragma unroll
    for (int kc = 0; kc < KC; ++kc) {
#pragma unroll
      for (int qg = 0; qg < 2; ++qg) {
        aH[qg] = __builtin_amdgcn_mfma_f32_16x16x32_bf16(ah[qg][kc], bh[kc], aH[qg], 0, 0, 0);
        aX[qg] = __builtin_amdgcn_mfma_f32_16x16x32_bf16(al[qg][kc], bh[kc], aX[qg], 0, 0, 0);
        aX[qg] = __builtin_amdgcn_mfma_f32_16x16x32_bf16(ah[qg][kc], bl[kc], aX[qg], 0, 0, 0);
      }
    }
    __builtin_amdgcn_s_setprio(0);
    // scores: query qg*16+(ln>>4)*4+r, cand t*TS+(ln&15)
    float s8[8];
#pragma unroll
    for (int qg = 0; qg < 2; ++qg)
#pragma unroll
      for (int r = 0; r < 4; ++r)
        s8[qg * 4 + r] = cn - 2.0f * (aH[qg][r] + aX[qg][r]);

    // reload this register set for tile t+2 (latency hidden under next step)
    if (t + 2 < NT) load_B<F>(Xh, Xl, sqn, cbase + (t + 2) * TS, ln, bh, bl, cn);

    // selection: 8 independent ballot groups, shfl-free appends
    const int ci = cbase + t * TS + (ln & 15);
#pragma unroll
    for (int qg = 0; qg < 2; ++qg)
#pragma unroll
      for (int r = 0; r < 4; ++r) {
        const int g = qg * 4 + r;
        float s = s8[g];
        unsigned long long m = __ballot(s < myth[g]);
        if (m) {
          if (s < myth[g]) {
            int qk = qg * 16 + ((ln & 48) >> 2) + r;
            int pos = cnt8[g] + __popcll(m & gmask & below);
            Bs[qk * LIST + pos] = s;
            Bi[qk * LIST + pos] = (ushort)ci;
          }
          cnt8[g] += __popcll(m & gmask);
          if (ln < 32 && (ln >> 4) == qg && (ln & 3) == r)
            bcnt += __popcll((m >> (((ln & 15) >> 2) * 16)) & 0xFFFFull);
        }
      }
    // overflow merges once per step: per-query appends/step <= 16, cap 32
    unsigned long long mm = __ballot(ln < 32 && bcnt > 16);
    if (mm) {
      do {
        int qk = __ffsll(mm) - 1;
        mm &= mm - 1;
        merge_q(qk);
      } while (mm);
#pragma unroll
      for (int qg = 0; qg < 2; ++qg)
#pragma unroll
        for (int r = 0; r < 4; ++r)
          myth[qg * 4 + r] = __shfl(thr_reg, qg * 16 + ((ln & 48) >> 2) + r);
    }
  };

#pragma unroll 1
  for (int t = 0; t < NT; t += 2) {
    step(b0h, b0l, cn0, t);
    step(b1h, b1l, cn1, t + 1);
  }

  // final flush
  {
    unsigned long long mm = __ballot(ln < 32 && bcnt > 0);
    while (mm) {
      int qk = __ffsll(mm) - 1;
      mm &= mm - 1;
      merge_q(qk);
    }
  }

  // write 32 queries x 32 candidates
#pragma unroll
  for (int k2 = 0; k2 < 16; ++k2) {
    int row = k2 * 2 + (ln >> 5);
    int col = ln & 31;
    out_cand[(size_t)(q0 + row) * (NSPLIT * LIST) + hf * LIST + col] = (int)Li[row * LIST + col];
  }
}

// Exact fp32 re-rank of the 256 union candidates -> true fp32 top-20 set.
// One wave per query; lane l handles candidates l, l+64, l+128, l+192.
template<int F>
__global__ __launch_bounds__(256) void refine_kernel(const float* __restrict__ X,
                                                     const float* __restrict__ sqn,
                                                     const int* __restrict__ cand,
                                                     int* __restrict__ out_idx) {
  constexpr int CW = NSPLIT * LIST;  // 256
  const int wv = threadIdx.x >> 6, ln = threadIdx.x & 63;
  const int q = blockIdx.x * 4 + wv;
  int c[4]; float s[4];
#pragma unroll
  for (int i = 0; i < 4; ++i) c[i] = cand[(size_t)q * CW + i * 64 + ln];
  const float* qrow = X + (size_t)q * F;
#pragma unroll
  for (int i = 0; i < 4; ++i) {
    const float* crow = X + (size_t)c[i] * F;
    float dot = 0.f;
#pragma unroll
    for (int d = 0; d < F; d += 4) {
      float4 qv = *(const float4*)(qrow + d);
      float4 cv = *(const float4*)(crow + d);
      dot += qv.x * cv.x + qv.y * cv.y + qv.z * cv.z + qv.w * cv.w;
    }
    s[i] = sqn[c[i]] - 2.0f * dot;
  }
  // rank by (score asc, index asc); eighths are disjoint -> no duplicates
  int rank[4] = {0, 0, 0, 0};
#pragma unroll 1
  for (int j = 0; j < 64; ++j) {
#pragma unroll
    for (int a = 0; a < 4; ++a) {
      float sa = __shfl(s[a], j);
      int   ca = __shfl(c[a], j);
#pragma unroll
      for (int b = 0; b < 4; ++b)
        rank[b] += (sa < s[b]) || (sa == s[b] && ca < c[b]);
    }
  }
#pragma unroll
  for (int i = 0; i < 4; ++i)
    if (rank[i] < KNN) out_idx[(size_t)q * KNN + rank[i]] = c[i];
}

// x1 = relu(pos @ W1 + b1) + bf16 hi/lo split + squared row norms.
__global__ __launch_bounds__(256) void mlp1_kernel(const float* __restrict__ pos,
                                                   const float* __restrict__ W1,
                                                   const float* __restrict__ b1,
                                                   float* __restrict__ x1,
                                                   ushort* __restrict__ xh,
                                                   ushort* __restrict__ xl,
                                                   float* __restrict__ sqn) {
  int i = blockIdx.x * 4 + (threadIdx.x >> 6);
  int o = threadIdx.x & 63;
  float p0 = pos[i * 3], p1 = pos[i * 3 + 1], p2 = pos[i * 3 + 2];
  float v = p0 * W1[o] + p1 * W1[64 + o] + p2 * W1[128 + o] + b1[o];
  v = fmaxf(v, 0.f);
  x1[(size_t)i * 64 + o] = v;
  __hip_bfloat16 h = __float2bfloat16(v);
  float hv = __bfloat162float(h);
  __hip_bfloat16 l2 = __float2bfloat16(v - hv);
  xh[(size_t)i * 64 + o] = *(ushort*)&h;
  xl[(size_t)i * 64 + o] = *(ushort*)&l2;
  float ss = v * v;
#pragma unroll
  for (int d = 32; d; d >>= 1) ss += __shfl_xor(ss, d);
  if (o == 0) sqn[i] = ss;
}

// Fused P = X@Wp + bias, Q = X@Wq (shared X staging). 4 rows x float4 each.
template<int K, int OUT>
__global__ __launch_bounds__(256) void linpq_kernel(const float* __restrict__ X,
                                                    const float* __restrict__ Wp,
                                                    const float* __restrict__ bp,
                                                    const float* __restrict__ Wq,
                                                    float* __restrict__ P,
                                                    float* __restrict__ Q) {
  constexpr int XD = OUT / 4;
  constexpr int YD = 256 / XD;
  constexpr int R = YD * 4;
  __shared__ float xs[R * K];
  const int tid = threadIdx.x;
  const int tx = tid % XD, ty = tid / XD;
  const size_t r0 = (size_t)blockIdx.x * R;
  const float4* Xv = (const float4*)(X + r0 * K);
  float4* xsv = (float4*)xs;
#pragma unroll
  for (int i2 = tid; i2 < R * K / 4; i2 += 256) xsv[i2] = Xv[i2];
  __syncthreads();
  float4 ap[4], aq[4];
#pragma unroll
  for (int i = 0; i < 4; i++) { ap[i] = make_float4(0,0,0,0); aq[i] = make_float4(0,0,0,0); }
  const float4* Wp4 = (const float4*)Wp;
  const float4* Wq4 = (const float4*)Wq;
#pragma unroll 4
  for (int k = 0; k < K; ++k) {
    float4 wp = Wp4[k * XD + tx];
    float4 wq = Wq4[k * XD + tx];
#pragma unroll
    for (int i = 0; i < 4; i++) {
      float xv = xs[(ty * 4 + i) * K + k];
      ap[i].x += xv * wp.x; ap[i].y += xv * wp.y; ap[i].z += xv * wp.z; ap[i].w += xv * wp.w;
      aq[i].x += xv * wq.x; aq[i].y += xv * wq.y; aq[i].z += xv * wq.z; aq[i].w += xv * wq.w;
    }
  }
  float4 bv = ((const float4*)bp)[tx];
#pragma unroll
  for (int i = 0; i < 4; i++) {
    float4 o;
    o.x = ap[i].x + bv.x; o.y = ap[i].y + bv.y; o.z = ap[i].z + bv.z; o.w = ap[i].w + bv.w;
    ((float4*)(P + (r0 + ty * 4 + i) * OUT))[tx] = o;
    ((float4*)(Q + (r0 + ty * 4 + i) * OUT))[tx] = aq[i];
  }
}

// Layer-1 epilogue fused: x2 = relu(P + max_j Q[nb]), plus hi/lo split + norms.
__global__ void maxpoolprep_kernel(const float* __restrict__ P, const float* __restrict__ Qm,
                                   const int* __restrict__ idx, float* __restrict__ xo,
                                   ushort* __restrict__ xh, ushort* __restrict__ xl,
                                   float* __restrict__ sqn) {
  __shared__ int nb[KNN];
  __shared__ float part[2];
  int i = blockIdx.x;
  if (threadIdx.x < KNN) nb[threadIdx.x] = idx[(size_t)i * KNN + threadIdx.x];
  __syncthreads();
  int o = threadIdx.x;  // 128 threads
  float m = -3.0e38f;
#pragma unroll
  for (int j = 0; j < KNN; j++) m = fmaxf(m, Qm[(size_t)nb[j] * 128 + o]);
  float v = fmaxf(P[(size_t)i * 128 + o] + m, 0.f);
  xo[(size_t)i * 128 + o] = v;
  __hip_bfloat16 h = __float2bfloat16(v);
  float hv = __bfloat162float(h);
  __hip_bfloat16 l2 = __float2bfloat16(v - hv);
  xh[(size_t)i * 128 + o] = *(ushort*)&h;
  xl[(size_t)i * 128 + o] = *(ushort*)&l2;
  float ss = v * v;
#pragma unroll
  for (int d = 32; d; d >>= 1) ss += __shfl_xor(ss, d);
  if ((threadIdx.x & 63) == 0) part[threadIdx.x >> 6] = ss;
  __syncthreads();
  if (threadIdx.x == 0) sqn[i] = part[0] + part[1];
}

// out_i = relu(P_i + max_j Q[idx[i][j]])
template<int OUT>
__global__ void maxpool_kernel(const float* __restrict__ P, const float* __restrict__ Q,
                               const int* __restrict__ idx, float* __restrict__ xo) {
  __shared__ int nb[KNN];
  int i = blockIdx.x;
  if (threadIdx.x < KNN) nb[threadIdx.x] = idx[(size_t)i * KNN + threadIdx.x];
  __syncthreads();
  int o = threadIdx.x;
  float m = -3.0e38f;
#pragma unroll
  for (int j = 0; j < KNN; j++) m = fmaxf(m, Q[(size_t)nb[j] * OUT + o]);
  float p = P[(size_t)i * OUT + o];
  xo[(size_t)i * OUT + o] = fmaxf(p + m, 0.f);
}

// C[N x OUT] = X[N x K] @ W[K x OUT] (+ bias). Register-tiled 4 rows x float4.
template<int K, int OUT, bool BIAS>
__global__ __launch_bounds__(256) void lin_kernel(const float* __restrict__ X,
                                                  const float* __restrict__ W,
                                                  const float* __restrict__ bias,
                                                  float* __restrict__ C) {
  constexpr int XD = OUT / 4;
  constexpr int YD = 256 / XD;
  constexpr int R = YD * 4;
  __shared__ float xs[R * K];
  const int tid = threadIdx.x;
  const int tx = tid % XD, ty = tid / XD;
  const size_t r0 = (size_t)blockIdx.x * R;
  const float4* Xv = (const float4*)(X + r0 * K);
  float4* xsv = (float4*)xs;
#pragma unroll
  for (int i2 = tid; i2 < R * K / 4; i2 += 256) xsv[i2] = Xv[i2];
  __syncthreads();
  float4 acc[4];
#pragma unroll
  for (int i = 0; i < 4; i++) acc[i] = make_float4(0.f, 0.f, 0.f, 0.f);
  const float4* W4 = (const float4*)W;
#pragma unroll 8
  for (int k = 0; k < K; ++k) {
    float4 wv = W4[k * XD + tx];
#pragma unroll
    for (int i = 0; i < 4; i++) {
      float xv = xs[(ty * 4 + i) * K + k];
      acc[i].x += xv * wv.x; acc[i].y += xv * wv.y;
      acc[i].z += xv * wv.z; acc[i].w += xv * wv.w;
    }
  }
  float4 bv = make_float4(0.f, 0.f, 0.f, 0.f);
  if (BIAS) bv = ((const float4*)bias)[tx];
#pragma unroll
  for (int i = 0; i < 4; i++) {
    float4 o;
    o.x = acc[i].x + bv.x; o.y = acc[i].y + bv.y;
    o.z = acc[i].z + bv.z; o.w = acc[i].w + bv.w;
    ((float4*)(C + (r0 + ty * 4 + i) * OUT))[tx] = o;
  }
}

// Wp[k][o] = We[k][o] - We[K+k][o]
__global__ void wsub_kernel(const float* __restrict__ We, float* __restrict__ Wp, int total) {
  int t = blockIdx.x * 256 + threadIdx.x;
  if (t < total) Wp[t] = We[t] - We[total + t];
}

extern "C" void kernel_launch(void* const* d_in, const int* in_sizes, int n_in,
                              void* d_out, int out_size, void* d_ws, size_t ws_size,
                              hipStream_t stream) {
  const float* pos = (const float*)d_in[0];
  const float* W1  = (const float*)d_in[1];
  const float* b1  = (const float*)d_in[2];
  const float* We1 = (const float*)d_in[3];
  const float* be1 = (const float*)d_in[4];
  const float* We2 = (const float*)d_in[5];
  const float* be2 = (const float*)d_in[6];
  const float* W2  = (const float*)d_in[7];
  const float* b2  = (const float*)d_in[8];
  float* out = (float*)d_out;

  const size_t N = N_PTS;
  float* ws  = (float*)d_ws;
  float* x1  = ws;               // N*64
  float* P1  = x1 + N * 64;      // N*128
  float* Q1  = P1 + N * 128;     // N*128
  float* x2  = Q1 + N * 128;     // N*128
  float* P2  = x2 + N * 128;     // N*256
  float* Q2  = P2 + N * 256;     // N*256
  float* x3  = Q2 + N * 256;     // N*256
  float* sqn = x3 + N * 256;     // N (x1 norms, then x2 norms)
  float* Wp1 = sqn + N;          // 64*128
  float* Wp2 = Wp1 + 64 * 128;   // 128*256
  int* idx1  = (int*)(Wp2 + 128 * 256);  // N*20
  int* idx2  = idx1 + N * KNN;           // N*20
  // cand aliases Q2's slot (N*256 ints == N*256 floats): fully consumed by
  // refine before Q2 is written by linpq (same stream, program order).
  int* cand  = (int*)Q2;
  ushort* X1h = (ushort*)(idx2 + N * KNN);  // N*64
  ushort* X1l = X1h + N * 64;               // N*64
  ushort* X2h = X1l + N * 64;               // N*128
  ushort* X2l = X2h + N * 128;              // N*128
  size_t need = (size_t)((char*)(X2l + N * 128) - (char*)d_ws);
  if (ws_size < need) return;  // insufficient scratch -> visible failure

  wsub_kernel<<<(64 * 128 + 255) / 256, 256, 0, stream>>>(We1, Wp1, 64 * 128);
  wsub_kernel<<<(128 * 256 + 255) / 256, 256, 0, stream>>>(We2, Wp2, 128 * 256);

  mlp1_kernel<<<N / 4, 256, 0, stream>>>(pos, W1, b1, x1, X1h, X1l, sqn);
  knn_kernel<64><<<(N / 32) * NSPLIT, 64, 0, stream>>>(X1h, X1l, sqn, cand);   // 4096 blocks
  refine_kernel<64><<<N / 4, 256, 0, stream>>>(x1, sqn, cand, idx1);
  linpq_kernel<64, 128><<<N / 32, 256, 0, stream>>>(x1, Wp1, be1, We1 + 64 * 128, P1, Q1);
  maxpoolprep_kernel<<<N, 128, 0, stream>>>(P1, Q1, idx1, x2, X2h, X2l, sqn);

  knn_kernel<128><<<(N / 32) * NSPLIT, 64, 0, stream>>>(X2h, X2l, sqn, cand);  // 4096 blocks
  refine_kernel<128><<<N / 4, 256, 0, stream>>>(x2, sqn, cand, idx2);
  linpq_kernel<128, 256><<<N / 16, 256, 0, stream>>>(x2, Wp2, be2, We2 + 128 * 256, P2, Q2);
  maxpool_kernel<256><<<N, 256, 0, stream>>>(P2, Q2, idx2, x3);

  lin_kernel<256, 128, true ><<<N / 32, 256, 0, stream>>>(x3, W2, b2, out);
}

// Round 12
// 2314.162 us; speedup vs baseline: 2.0702x; 1.5917x over previous
//
#include <hip/hip_runtime.h>
#include <hip/hip_bf16.h>

#define N_PTS 16384
#define KNN   20
#define LIST  32   // approx-stage list width per candidate-quarter (refine is exact)
#define NSPLIT 4   // candidate-range split

typedef __attribute__((ext_vector_type(8))) short bf16x8;
typedef __attribute__((ext_vector_type(4))) float f32x4;

// Load B fragments (16 candidate rows x 32k-chunk) for one tile, direct
// global -> registers. Row = c0 + (ln&15), chunk = kc*4 + (ln>>4).
template<int F>
__device__ __forceinline__ void load_B(const ushort* __restrict__ Xh,
                                       const ushort* __restrict__ Xl,
                                       const float* __restrict__ sqn,
                                       int c0, int ln,
                                       bf16x8 (&bh)[F / 32], bf16x8 (&bl)[F / 32],
                                       float& cn) {
  constexpr int KC = F / 32;
  const int apc = ln >> 4;
  size_t roff = (size_t)(c0 + (ln & 15)) * F;
#pragma unroll
  for (int kc = 0; kc < KC; ++kc) {
    size_t off = roff + (size_t)(kc * 4 + apc) * 8;
    bh[kc] = *(const bf16x8*)(Xh + off);
    bl[kc] = *(const bf16x8*)(Xl + off);
  }
  cn = sqn[c0 + (ln & 15)];
}

// Fused bf16x3-MFMA distance + buffered top-32 kNN over a QUARTER of the
// candidate range. ONE wave per block, 16 queries per wave (query-split for
// occupancy: total selection work is NSPLIT-invariant, per-block chains
// halve vs 32q/wave). Candidates stream global->reg (L2-resident, no
// barriers). Selection: shfl-free parallel appends + rare bitonic merges.
// NOTE: keep __launch_bounds__(64,2) — (64,4) forces VGPR<=128 and SPILLS
// (round-10: WRITE_SIZE 8MB->1.9GB, 2.7x slower). Do not tighten.
template<int F>
__global__ __launch_bounds__(64, 2) void knn_kernel(const ushort* __restrict__ Xh,
                                                    const ushort* __restrict__ Xl,
                                                    const float* __restrict__ sqn,
                                                    int* __restrict__ out_cand) {
  constexpr int KC = F / 32;            // 32-k chunks per row
  constexpr int NC = N_PTS / NSPLIT;    // candidates per block (4096)
  constexpr int TS = 16;                // candidate tile (one MFMA column tile)
  constexpr int NT = NC / TS;           // 256 steps
  __shared__ float  Bs[16 * LIST];      // survivor scores
  __shared__ ushort Bi[16 * LIST];      // survivor indices
  __shared__ float  Ld[16 * LIST];      // sorted distances
  __shared__ ushort Li[16 * LIST];      // sorted indices

  const int ln = threadIdx.x;
  const int q0 = (int)(blockIdx.x >> 2) * 16;
  const int hf = blockIdx.x & 3;
  const int cbase = hf * NC;

  // init sorted lists (16 queries x 32 entries = 512 = 8*64)
#pragma unroll
  for (int k = 0; k < 8; ++k) {
    int idx = k * 64 + ln;
    Ld[idx] = 3.0e38f; Li[idx] = 0;
  }
  float thr_reg = 3.0e38f;   // lane j<16: 32nd-best of query j
  float myth[4];             // own-slot thresholds: myth[r] for q=(ln>>4)*4+r
  int   cnt4[4];             // per-lane replicated buffered-count of slot's queries
#pragma unroll
  for (int i = 0; i < 4; ++i) { myth[i] = 3.0e38f; cnt4[i] = 0; }
  int bcnt = 0;              // lane j<16: buffered count of query j

  // wave-collective merge of query qk's buffer into its sorted top-32
  auto merge_q = [&](int qk) {
    int cnt = __shfl(bcnt, qk);
    int lrow = qk * LIST;
    float key; int id;
    if (ln < 32) { key = Ld[lrow + ln]; id = (int)Li[lrow + ln]; }
    else {
      int j = ln - 32;
      bool v = j < cnt;
      key = v ? Bs[lrow + j] : 3.0e38f;
      id  = v ? (int)Bi[lrow + j] : 65535;
    }
#pragma unroll
    for (int kk = 2; kk <= 64; kk <<= 1) {
#pragma unroll
      for (int jj = kk >> 1; jj > 0; jj >>= 1) {
        float ok = __shfl_xor(key, jj);
        int   oi = __shfl_xor(id, jj);
        bool pless = (ok < key) || (ok == key && oi < id);
        bool take = pless == (((ln & jj) == 0) == ((ln & kk) == 0));
        key = take ? ok : key;
        id  = take ? oi : id;
      }
    }
    if (ln < 32) { Ld[lrow + ln] = key; Li[lrow + ln] = (ushort)id; }
    float tnew = __shfl(key, 31);
    thr_reg = (ln == qk) ? tnew : thr_reg;
    bcnt    = (ln == qk) ? 0 : bcnt;
    // reset the replicated count for the merged query (static indexing)
    int slot = qk >> 2;
    int g = qk & 3;
#pragma unroll
    for (int i = 0; i < 4; ++i)
      if (i == g && (ln >> 4) == slot) cnt4[i] = 0;
  };

  // A fragments: 16 query rows x KC chunks, hi/lo — direct from global
  bf16x8 ah[KC], al[KC];
  {
    const int apc = ln >> 4;
#pragma unroll
    for (int kc = 0; kc < KC; ++kc) {
      size_t off = (size_t)(q0 + (ln & 15)) * F + (size_t)(kc * 4 + apc) * 8;
      ah[kc] = *(const bf16x8*)(Xh + off);
      al[kc] = *(const bf16x8*)(Xl + off);
    }
  }

  // register double-buffered B tiles (named sets — no runtime indexing)
  bf16x8 b0h[KC], b0l[KC], b1h[KC], b1l[KC];
  float cn0, cn1;
  load_B<F>(Xh, Xl, sqn, cbase, ln, b0h, b0l, cn0);
  load_B<F>(Xh, Xl, sqn, cbase + TS, ln, b1h, b1l, cn1);

  const unsigned long long gmask = 0xFFFFull << (ln & 48);
  const unsigned long long below = (1ull << ln) - 1;

  // one pipeline step: MFMA(tile t) -> scores -> reload(t+2) -> selection
  auto step = [&](bf16x8 (&bh)[KC], bf16x8 (&bl)[KC], float& cn, int t) {
    f32x4 aH = {0.f, 0.f, 0.f, 0.f}, aX = {0.f, 0.f, 0.f, 0.f};
    __builtin_amdgcn_s_setprio(1);
#pragma unroll
    for (int kc = 0; kc < KC; ++kc) {
      aH = __builtin_amdgcn_mfma_f32_16x16x32_bf16(ah[kc], bh[kc], aH, 0, 0, 0);
      aX = __builtin_amdgcn_mfma_f32_16x16x32_bf16(al[kc], bh[kc], aX, 0, 0, 0);
      aX = __builtin_amdgcn_mfma_f32_16x16x32_bf16(ah[kc], bl[kc], aX, 0, 0, 0);
    }
    __builtin_amdgcn_s_setprio(0);
    // scores: query (ln>>4)*4+r, cand t*TS+(ln&15)
    float s4[4];
#pragma unroll
    for (int r = 0; r < 4; ++r) s4[r] = cn - 2.0f * (aH[r] + aX[r]);

    // reload this register set for tile t+2 (latency hidden under next step)
    if (t + 2 < NT) load_B<F>(Xh, Xl, sqn, cbase + (t + 2) * TS, ln, bh, bl, cn);

    // selection: 4 independent ballot groups, shfl-free appends
    const int ci = cbase + t * TS + (ln & 15);
#pragma unroll
    for (int r = 0; r < 4; ++r) {
      float s = s4[r];
      unsigned long long m = __ballot(s < myth[r]);
      if (m) {
        if (s < myth[r]) {
          int qk = ((ln >> 4) << 2) + r;
          int pos = cnt4[r] + __popcll(m & gmask & below);
          Bs[qk * LIST + pos] = s;
          Bi[qk * LIST + pos] = (ushort)ci;
        }
        cnt4[r] += __popcll(m & gmask);
        if (ln < 16 && (ln & 3) == r)
          bcnt += __popcll((m >> ((ln >> 2) * 16)) & 0xFFFFull);
      }
    }
    // overflow merges once per step: per-query appends/step <= 16, cap 32
    unsigned long long mm = __ballot(ln < 16 && bcnt > 16);
    if (mm) {
      do {
        int qk = __ffsll(mm) - 1;
        mm &= mm - 1;
        merge_q(qk);
      } while (mm);
#pragma unroll
      for (int r = 0; r < 4; ++r)
        myth[r] = __shfl(thr_reg, ((ln >> 4) << 2) + r);
    }
  };

#pragma unroll 1
  for (int t = 0; t < NT; t += 2) {
    step(b0h, b0l, cn0, t);
    step(b1h, b1l, cn1, t + 1);
  }

  // final flush
  {
    unsigned long long mm = __ballot(ln < 16 && bcnt > 0);
    while (mm) {
      int qk = __ffsll(mm) - 1;
      mm &= mm - 1;
      merge_q(qk);
    }
  }

  // write 16 queries x 32 candidates
#pragma unroll
  for (int k2 = 0; k2 < 8; ++k2) {
    int row = k2 * 2 + (ln >> 5);
    int col = ln & 31;
    out_cand[(size_t)(q0 + row) * (NSPLIT * LIST) + hf * LIST + col] = (int)Li[row * LIST + col];
  }
}

// Exact fp32 re-rank of the 128 union candidates -> true fp32 top-20 set.
// One wave per query; lane l handles candidates l and l+64.
template<int F>
__global__ __launch_bounds__(256) void refine_kernel(const float* __restrict__ X,
                                                     const float* __restrict__ sqn,
                                                     const int* __restrict__ cand,
                                                     int* __restrict__ out_idx) {
  constexpr int CW = NSPLIT * LIST;  // 128
  const int wv = threadIdx.x >> 6, ln = threadIdx.x & 63;
  const int q = blockIdx.x * 4 + wv;
  int c0 = cand[(size_t)q * CW + ln];
  int c1 = cand[(size_t)q * CW + 64 + ln];
  const float* qrow = X + (size_t)q * F;
  const float* crow0 = X + (size_t)c0 * F;
  const float* crow1 = X + (size_t)c1 * F;
  float dot0 = 0.f, dot1 = 0.f;
#pragma unroll
  for (int d = 0; d < F; d += 4) {
    float4 qv = *(const float4*)(qrow + d);
    float4 v0 = *(const float4*)(crow0 + d);
    float4 v1 = *(const float4*)(crow1 + d);
    dot0 += qv.x * v0.x + qv.y * v0.y + qv.z * v0.z + qv.w * v0.w;
    dot1 += qv.x * v1.x + qv.y * v1.y + qv.z * v1.z + qv.w * v1.w;
  }
  float s0 = sqn[c0] - 2.0f * dot0;
  float s1 = sqn[c1] - 2.0f * dot1;
  // rank by (score asc, index asc); quarters are disjoint -> no duplicates
  int rank0 = 0, rank1 = 0;
#pragma unroll 1
  for (int j = 0; j < 64; ++j) {
    float a0 = __shfl(s0, j); int i0 = __shfl(c0, j);
    float a1 = __shfl(s1, j); int i1 = __shfl(c1, j);
    rank0 += ((a0 < s0) || (a0 == s0 && i0 < c0)) + ((a1 < s0) || (a1 == s0 && i1 < c0));
    rank1 += ((a0 < s1) || (a0 == s1 && i0 < c1)) + ((a1 < s1) || (a1 == s1 && i1 < c1));
  }
  if (rank0 < KNN) out_idx[(size_t)q * KNN + rank0] = c0;
  if (rank1 < KNN) out_idx[(size_t)q * KNN + rank1] = c1;
}

// x1 = relu(pos @ W1 + b1) + bf16 hi/lo split + squared row norms.
__global__ __launch_bounds__(256) void mlp1_kernel(const float* __restrict__ pos,
                                                   const float* __restrict__ W1,
                                                   const float* __restrict__ b1,
                                                   float* __restrict__ x1,
                                                   ushort* __restrict__ xh,
                                                   ushort* __restrict__ xl,
                                                   float* __restrict__ sqn) {
  int i = blockIdx.x * 4 + (threadIdx.x >> 6);
  int o = threadIdx.x & 63;
  float p0 = pos[i * 3], p1 = pos[i * 3 + 1], p2 = pos[i * 3 + 2];
  float v = p0 * W1[o] + p1 * W1[64 + o] + p2 * W1[128 + o] + b1[o];
  v = fmaxf(v, 0.f);
  x1[(size_t)i * 64 + o] = v;
  __hip_bfloat16 h = __float2bfloat16(v);
  float hv = __bfloat162float(h);
  __hip_bfloat16 l2 = __float2bfloat16(v - hv);
  xh[(size_t)i * 64 + o] = *(ushort*)&h;
  xl[(size_t)i * 64 + o] = *(ushort*)&l2;
  float ss = v * v;
#pragma unroll
  for (int d = 32; d; d >>= 1) ss += __shfl_xor(ss, d);
  if (o == 0) sqn[i] = ss;
}

// Fused P = X@Wp + bias, Q = X@Wq (shared X staging). 4 rows x float4 each.
template<int K, int OUT>
__global__ __launch_bounds__(256) void linpq_kernel(const float* __restrict__ X,
                                                    const float* __restrict__ Wp,
                                                    const float* __restrict__ bp,
                                                    const float* __restrict__ Wq,
                                                    float* __restrict__ P,
                                                    float* __restrict__ Q) {
  constexpr int XD = OUT / 4;
  constexpr int YD = 256 / XD;
  constexpr int R = YD * 4;
  __shared__ float xs[R * K];
  const int tid = threadIdx.x;
  const int tx = tid % XD, ty = tid / XD;
  const size_t r0 = (size_t)blockIdx.x * R;
  const float4* Xv = (const float4*)(X + r0 * K);
  float4* xsv = (float4*)xs;
#pragma unroll
  for (int i2 = tid; i2 < R * K / 4; i2 += 256) xsv[i2] = Xv[i2];
  __syncthreads();
  float4 ap[4], aq[4];
#pragma unroll
  for (int i = 0; i < 4; i++) { ap[i] = make_float4(0,0,0,0); aq[i] = make_float4(0,0,0,0); }
  const float4* Wp4 = (const float4*)Wp;
  const float4* Wq4 = (const float4*)Wq;
#pragma unroll 4
  for (int k = 0; k < K; ++k) {
    float4 wp = Wp4[k * XD + tx];
    float4 wq = Wq4[k * XD + tx];
#pragma unroll
    for (int i = 0; i < 4; i++) {
      float xv = xs[(ty * 4 + i) * K + k];
      ap[i].x += xv * wp.x; ap[i].y += xv * wp.y; ap[i].z += xv * wp.z; ap[i].w += xv * wp.w;
      aq[i].x += xv * wq.x; aq[i].y += xv * wq.y; aq[i].z += xv * wq.z; aq[i].w += xv * wq.w;
    }
  }
  float4 bv = ((const float4*)bp)[tx];
#pragma unroll
  for (int i = 0; i < 4; i++) {
    float4 o;
    o.x = ap[i].x + bv.x; o.y = ap[i].y + bv.y; o.z = ap[i].z + bv.z; o.w = ap[i].w + bv.w;
    ((float4*)(P + (r0 + ty * 4 + i) * OUT))[tx] = o;
    ((float4*)(Q + (r0 + ty * 4 + i) * OUT))[tx] = aq[i];
  }
}

// Layer-1 epilogue fused: x2 = relu(P + max_j Q[nb]), plus hi/lo split + norms.
__global__ void maxpoolprep_kernel(const float* __restrict__ P, const float* __restrict__ Qm,
                                   const int* __restrict__ idx, float* __restrict__ xo,
                                   ushort* __restrict__ xh, ushort* __restrict__ xl,
                                   float* __restrict__ sqn) {
  __shared__ int nb[KNN];
  __shared__ float part[2];
  int i = blockIdx.x;
  if (threadIdx.x < KNN) nb[threadIdx.x] = idx[(size_t)i * KNN + threadIdx.x];
  __syncthreads();
  int o = threadIdx.x;  // 128 threads
  float m = -3.0e38f;
#pragma unroll
  for (int j = 0; j < KNN; j++) m = fmaxf(m, Qm[(size_t)nb[j] * 128 + o]);
  float v = fmaxf(P[(size_t)i * 128 + o] + m, 0.f);
  xo[(size_t)i * 128 + o] = v;
  __hip_bfloat16 h = __float2bfloat16(v);
  float hv = __bfloat162float(h);
  __hip_bfloat16 l2 = __float2bfloat16(v - hv);
  xh[(size_t)i * 128 + o] = *(ushort*)&h;
  xl[(size_t)i * 128 + o] = *(ushort*)&l2;
  float ss = v * v;
#pragma unroll
  for (int d = 32; d; d >>= 1) ss += __shfl_xor(ss, d);
  if ((threadIdx.x & 63) == 0) part[threadIdx.x >> 6] = ss;
  __syncthreads();
  if (threadIdx.x == 0) sqn[i] = part[0] + part[1];
}

// out_i = relu(P_i + max_j Q[idx[i][j]])
template<int OUT>
__global__ void maxpool_kernel(const float* __restrict__ P, const float* __restrict__ Q,
                               const int* __restrict__ idx, float* __restrict__ xo) {
  __shared__ int nb[KNN];
  int i = blockIdx.x;
  if (threadIdx.x < KNN) nb[threadIdx.x] = idx[(size_t)i * KNN + threadIdx.x];
  __syncthreads();
  int o = threadIdx.x;
  float m = -3.0e38f;
#pragma unroll
  for (int j = 0; j < KNN; j++) m = fmaxf(m, Q[(size_t)nb[j] * OUT + o]);
  float p = P[(size_t)i * OUT + o];
  xo[(size_t)i * OUT + o] = fmaxf(p + m, 0.f);
}

// C[N x OUT] = X[N x K] @ W[K x OUT] (+ bias). Register-tiled 4 rows x float4.
template<int K, int OUT, bool BIAS>
__global__ __launch_bounds__(256) void lin_kernel(const float* __restrict__ X,
                                                  const float* __restrict__ W,
                                                  const float* __restrict__ bias,
                                                  float* __restrict__ C) {
  constexpr int XD = OUT / 4;
  constexpr int YD = 256 / XD;
  constexpr int R = YD * 4;
  __shared__ float xs[R * K];
  const int tid = threadIdx.x;
  const int tx = tid % XD, ty = tid / XD;
  const size_t r0 = (size_t)blockIdx.x * R;
  const float4* Xv = (const float4*)(X + r0 * K);
  float4* xsv = (float4*)xs;
#pragma unroll
  for (int i2 = tid; i2 < R * K / 4; i2 += 256) xsv[i2] = Xv[i2];
  __syncthreads();
  float4 acc[4];
#pragma unroll
  for (int i = 0; i < 4; i++) acc[i] = make_float4(0.f, 0.f, 0.f, 0.f);
  const float4* W4 = (const float4*)W;
#pragma unroll 8
  for (int k = 0; k < K; ++k) {
    float4 wv = W4[k * XD + tx];
#pragma unroll
    for (int i = 0; i < 4; i++) {
      float xv = xs[(ty * 4 + i) * K + k];
      acc[i].x += xv * wv.x; acc[i].y += xv * wv.y;
      acc[i].z += xv * wv.z; acc[i].w += xv * wv.w;
    }
  }
  float4 bv = make_float4(0.f, 0.f, 0.f, 0.f);
  if (BIAS) bv = ((const float4*)bias)[tx];
#pragma unroll
  for (int i = 0; i < 4; i++) {
    float4 o;
    o.x = acc[i].x + bv.x; o.y = acc[i].y + bv.y;
    o.z = acc[i].z + bv.z; o.w = acc[i].w + bv.w;
    ((float4*)(C + (r0 + ty * 4 + i) * OUT))[tx] = o;
  }
}

// Wp[k][o] = We[k][o] - We[K+k][o]
__global__ void wsub_kernel(const float* __restrict__ We, float* __restrict__ Wp, int total) {
  int t = blockIdx.x * 256 + threadIdx.x;
  if (t < total) Wp[t] = We[t] - We[total + t];
}

extern "C" void kernel_launch(void* const* d_in, const int* in_sizes, int n_in,
                              void* d_out, int out_size, void* d_ws, size_t ws_size,
                              hipStream_t stream) {
  const float* pos = (const float*)d_in[0];
  const float* W1  = (const float*)d_in[1];
  const float* b1  = (const float*)d_in[2];
  const float* We1 = (const float*)d_in[3];
  const float* be1 = (const float*)d_in[4];
  const float* We2 = (const float*)d_in[5];
  const float* be2 = (const float*)d_in[6];
  const float* W2  = (const float*)d_in[7];
  const float* b2  = (const float*)d_in[8];
  float* out = (float*)d_out;

  const size_t N = N_PTS;
  float* ws  = (float*)d_ws;
  float* x1  = ws;               // N*64
  float* P1  = x1 + N * 64;      // N*128
  float* Q1  = P1 + N * 128;     // N*128
  float* x2  = Q1 + N * 128;     // N*128
  float* P2  = x2 + N * 128;     // N*256
  float* Q2  = P2 + N * 256;     // N*256
  float* x3  = Q2 + N * 256;     // N*256
  float* sqn = x3 + N * 256;     // N (x1 norms, then x2 norms)
  float* Wp1 = sqn + N;          // 64*128
  float* Wp2 = Wp1 + 64 * 128;   // 128*256
  int* idx1  = (int*)(Wp2 + 128 * 256);  // N*20
  int* idx2  = idx1 + N * KNN;           // N*20
  // cand aliases Q2's slot (N*128 ints <= N*256 floats): fully consumed by
  // refine before Q2 is written by linpq (same stream, program order).
  int* cand  = (int*)Q2;
  ushort* X1h = (ushort*)(idx2 + N * KNN);  // N*64
  ushort* X1l = X1h + N * 64;               // N*64
  ushort* X2h = X1l + N * 64;               // N*128
  ushort* X2l = X2h + N * 128;              // N*128
  size_t need = (size_t)((char*)(X2l + N * 128) - (char*)d_ws);
  if (ws_size < need) return;  // insufficient scratch -> visible failure

  wsub_kernel<<<(64 * 128 + 255) / 256, 256, 0, stream>>>(We1, Wp1, 64 * 128);
  wsub_kernel<<<(128 * 256 + 255) / 256, 256, 0, stream>>>(We2, Wp2, 128 * 256);

  mlp1_kernel<<<N / 4, 256, 0, stream>>>(pos, W1, b1, x1, X1h, X1l, sqn);
  knn_kernel<64><<<(N / 16) * NSPLIT, 64, 0, stream>>>(X1h, X1l, sqn, cand);   // 4096 blocks
  refine_kernel<64><<<N / 4, 256, 0, stream>>>(x1, sqn, cand, idx1);
  linpq_kernel<64, 128><<<N / 32, 256, 0, stream>>>(x1, Wp1, be1, We1 + 64 * 128, P1, Q1);
  maxpoolprep_kernel<<<N, 128, 0, stream>>>(P1, Q1, idx1, x2, X2h, X2l, sqn);

  knn_kernel<128><<<(N / 16) * NSPLIT, 64, 0, stream>>>(X2h, X2l, sqn, cand);  // 4096 blocks
  refine_kernel<128><<<N / 4, 256, 0, stream>>>(x2, sqn, cand, idx2);
  linpq_kernel<128, 256><<<N / 16, 256, 0, stream>>>(x2, Wp2, be2, We2 + 128 * 256, P2, Q2);
  maxpool_kernel<256><<<N, 256, 0, stream>>>(P2, Q2, idx2, x3);

  lin_kernel<256, 128, true ><<<N / 32, 256, 0, stream>>>(x3, W2, b2, out);
}

// Round 13
// 2164.603 us; speedup vs baseline: 2.2133x; 1.0691x over previous
//
#include <hip/hip_runtime.h>
#include <hip/hip_bf16.h>

#define N_PTS 16384
#define KNN   20
#define LIST  32   // approx-stage list width per candidate-quarter (refine is exact)
#define NSPLIT 4   // candidate-range split

typedef __attribute__((ext_vector_type(8))) short bf16x8;
typedef __attribute__((ext_vector_type(4))) float f32x4;

// Load B fragments (16 candidate rows x 32k-chunk) for one tile, direct
// global -> registers. Row = c0 + (ln&15), chunk = kc*4 + (ln>>4).
template<int F>
__device__ __forceinline__ void load_B(const ushort* __restrict__ Xh,
                                       const ushort* __restrict__ Xl,
                                       const float* __restrict__ sqn,
                                       int c0, int ln,
                                       bf16x8 (&bh)[F / 32], bf16x8 (&bl)[F / 32],
                                       float& cn) {
  constexpr int KC = F / 32;
  const int apc = ln >> 4;
  size_t roff = (size_t)(c0 + (ln & 15)) * F;
#pragma unroll
  for (int kc = 0; kc < KC; ++kc) {
    size_t off = roff + (size_t)(kc * 4 + apc) * 8;
    bh[kc] = *(const bf16x8*)(Xh + off);
    bl[kc] = *(const bf16x8*)(Xl + off);
  }
  cn = sqn[c0 + (ln & 15)];
}

// Fused bf16x3-MFMA distance + buffered top-32 kNN over a QUARTER of the
// candidate range. ONE wave per block (64 thr), 32 queries per wave (two
// 16-row A groups sharing every B fragment). Candidates stream global->reg,
// DEPTH-4 register pipeline (4 named B sets; load->use distance ~3 steps
// covers L2/HBM latency). No barriers. Selection: parallel survivor appends
// into per-query LDS buffers + rare wave-collective bitonic merges.
// NOTE: keep __launch_bounds__(64,2) — (64,4) forces VGPR<=128 and SPILLS
// (round-10: WRITE_SIZE 8MB->1.9GB, 2.7x slower). Grid gives 2 waves/SIMD,
// so VGPR up to 256 costs nothing.
template<int F>
__global__ __launch_bounds__(64, 2) void knn_kernel(const ushort* __restrict__ Xh,
                                                    const ushort* __restrict__ Xl,
                                                    const float* __restrict__ sqn,
                                                    int* __restrict__ out_cand) {
  constexpr int KC = F / 32;            // 32-k chunks per row
  constexpr int NC = N_PTS / NSPLIT;    // candidates per block
  constexpr int TS = 16;                // candidate tile (one MFMA column tile)
  constexpr int NT = NC / TS;           // 256 steps
  __shared__ float  Bs[32 * LIST];      // survivor scores
  __shared__ ushort Bi[32 * LIST];      // survivor indices
  __shared__ float  Ld[32 * LIST];      // sorted distances
  __shared__ ushort Li[32 * LIST];      // sorted indices

  const int ln = threadIdx.x;
  const int q0 = (int)(blockIdx.x >> 2) * 32;
  const int hf = blockIdx.x & 3;
  const int cbase = hf * NC;

  // init sorted lists (32 queries x 32 entries)
#pragma unroll
  for (int k = 0; k < 16; ++k) {
    int idx = k * 64 + ln;
    Ld[idx] = 3.0e38f; Li[idx] = 0;
  }
  float thr_reg = 3.0e38f;   // lane j<32: 32nd-best of query j
  float myth[8];             // own-score thresholds: [qg*4+r] for q=qg*16+(ln>>4)*4+r
#pragma unroll
  for (int i = 0; i < 8; ++i) myth[i] = 3.0e38f;
  int bcnt = 0;              // lane j<32: buffered count of query j

  // wave-collective merge of query qk's buffer into its sorted top-32
  auto merge_q = [&](int qk) {
    int cnt = __shfl(bcnt, qk);
    int lrow = qk * LIST;
    float key; int id;
    if (ln < 32) { key = Ld[lrow + ln]; id = (int)Li[lrow + ln]; }
    else {
      int j = ln - 32;
      bool v = j < cnt;
      key = v ? Bs[lrow + j] : 3.0e38f;
      id  = v ? (int)Bi[lrow + j] : 65535;
    }
#pragma unroll
    for (int kk = 2; kk <= 64; kk <<= 1) {
#pragma unroll
      for (int jj = kk >> 1; jj > 0; jj >>= 1) {
        float ok = __shfl_xor(key, jj);
        int   oi = __shfl_xor(id, jj);
        bool pless = (ok < key) || (ok == key && oi < id);
        bool take = pless == (((ln & jj) == 0) == ((ln & kk) == 0));
        key = take ? ok : key;
        id  = take ? oi : id;
      }
    }
    if (ln < 32) { Ld[lrow + ln] = key; Li[lrow + ln] = (ushort)id; }
    float tnew = __shfl(key, 31);
    thr_reg = (ln == qk) ? tnew : thr_reg;
    bcnt    = (ln == qk) ? 0 : bcnt;
  };

  // A fragments: 2 query groups x KC chunks, hi/lo — direct from global
  bf16x8 ah[2][KC], al[2][KC];
  {
    const int apc = ln >> 4;
#pragma unroll
    for (int qg = 0; qg < 2; ++qg)
#pragma unroll
      for (int kc = 0; kc < KC; ++kc) {
        size_t off = (size_t)(q0 + qg * 16 + (ln & 15)) * F + (size_t)(kc * 4 + apc) * 8;
        ah[qg][kc] = *(const bf16x8*)(Xh + off);
        al[qg][kc] = *(const bf16x8*)(Xl + off);
      }
  }

  // DEPTH-4 register pipeline: four named B sets (no runtime indexing)
  bf16x8 b0h[KC], b0l[KC], b1h[KC], b1l[KC];
  bf16x8 b2h[KC], b2l[KC], b3h[KC], b3l[KC];
  float cn0, cn1, cn2, cn3;
  load_B<F>(Xh, Xl, sqn, cbase,          ln, b0h, b0l, cn0);
  load_B<F>(Xh, Xl, sqn, cbase + TS,     ln, b1h, b1l, cn1);
  load_B<F>(Xh, Xl, sqn, cbase + 2 * TS, ln, b2h, b2l, cn2);
  load_B<F>(Xh, Xl, sqn, cbase + 3 * TS, ln, b3h, b3l, cn3);

  // one pipeline step: MFMA(tile t) -> scores -> reload(t+4) -> selection
  auto step = [&](bf16x8 (&bh)[KC], bf16x8 (&bl)[KC], float& cn, int t) {
    f32x4 aH[2], aX[2];
#pragma unroll
    for (int qg = 0; qg < 2; ++qg) { aH[qg] = (f32x4){0,0,0,0}; aX[qg] = (f32x4){0,0,0,0}; }
    __builtin_amdgcn_s_setprio(1);
#pragma unroll
    for (int kc = 0; kc < KC; ++kc) {
#pragma unroll
      for (int qg = 0; qg < 2; ++qg) {
        aH[qg] = __builtin_amdgcn_mfma_f32_16x16x32_bf16(ah[qg][kc], bh[kc], aH[qg], 0, 0, 0);
        aX[qg] = __builtin_amdgcn_mfma_f32_16x16x32_bf16(al[qg][kc], bh[kc], aX[qg], 0, 0, 0);
        aX[qg] = __builtin_amdgcn_mfma_f32_16x16x32_bf16(ah[qg][kc], bl[kc], aX[qg], 0, 0, 0);
      }
    }
    __builtin_amdgcn_s_setprio(0);
    // scores for this lane: query qg*16+(ln>>4)*4+r, cand t*TS+(ln&15)
    float s8[8];
#pragma unroll
    for (int qg = 0; qg < 2; ++qg)
#pragma unroll
      for (int r = 0; r < 4; ++r)
        s8[qg * 4 + r] = cn - 2.0f * (aH[qg][r] + aX[qg][r]);

    // reload this register set for tile t+4 (3-step distance covers latency)
    if (t + 4 < NT) load_B<F>(Xh, Xl, sqn, cbase + (t + 4) * TS, ln, bh, bl, cn);

    // selection: 8 disjoint-query ballot groups, parallel appends
    const int ci = cbase + t * TS + (ln & 15);
#pragma unroll
    for (int qg = 0; qg < 2; ++qg)
#pragma unroll
      for (int r = 0; r < 4; ++r) {
        float s = s8[qg * 4 + r];
        unsigned long long m = __ballot(s < myth[qg * 4 + r]);
        if (m) {
          int qk = qg * 16 + ((ln & 48) >> 2) + r;
          int basec = __shfl(bcnt, qk);
          if (s < myth[qg * 4 + r]) {
            int pos = basec +
                __popcll(m & (0xFFFFull << (ln & 48)) & ((1ull << ln) - 1));
            Bs[qk * LIST + pos] = s;
            Bi[qk * LIST + pos] = (ushort)ci;
          }
          if (ln < 32 && (ln >> 4) == qg && (ln & 3) == r)
            bcnt += __popcll((m >> (((ln & 15) >> 2) * 16)) & 0xFFFFull);
        }
      }
    // overflow merges once per step: per-query appends/step <= 16, cap 32
    unsigned long long mm = __ballot(ln < 32 && bcnt > 16);
    if (mm) {
      do {
        int qk = __ffsll(mm) - 1;
        mm &= mm - 1;
        merge_q(qk);
      } while (mm);
#pragma unroll
      for (int qg = 0; qg < 2; ++qg)
#pragma unroll
        for (int r = 0; r < 4; ++r)
          myth[qg * 4 + r] = __shfl(thr_reg, qg * 16 + ((ln & 48) >> 2) + r);
    }
  };

#pragma unroll 1
  for (int t = 0; t < NT; t += 4) {
    step(b0h, b0l, cn0, t);
    step(b1h, b1l, cn1, t + 1);
    step(b2h, b2l, cn2, t + 2);
    step(b3h, b3l, cn3, t + 3);
  }

  // final flush
  {
    unsigned long long mm = __ballot(ln < 32 && bcnt > 0);
    while (mm) {
      int qk = __ffsll(mm) - 1;
      mm &= mm - 1;
      merge_q(qk);
    }
  }

  // write 32 queries x 32 candidates
#pragma unroll
  for (int k2 = 0; k2 < 16; ++k2) {
    int row = k2 * 2 + (ln >> 5);
    int col = ln & 31;
    out_cand[(size_t)(q0 + row) * (NSPLIT * LIST) + hf * LIST + col] = (int)Li[row * LIST + col];
  }
}

// Exact fp32 re-rank of the 128 union candidates -> true fp32 top-20 set.
// One wave per query; lane l handles candidates l and l+64.
template<int F>
__global__ __launch_bounds__(256) void refine_kernel(const float* __restrict__ X,
                                                     const float* __restrict__ sqn,
                                                     const int* __restrict__ cand,
                                                     int* __restrict__ out_idx) {
  constexpr int CW = NSPLIT * LIST;  // 128
  const int wv = threadIdx.x >> 6, ln = threadIdx.x & 63;
  const int q = blockIdx.x * 4 + wv;
  int c0 = cand[(size_t)q * CW + ln];
  int c1 = cand[(size_t)q * CW + 64 + ln];
  const float* qrow = X + (size_t)q * F;
  const float* crow0 = X + (size_t)c0 * F;
  const float* crow1 = X + (size_t)c1 * F;
  float dot0 = 0.f, dot1 = 0.f;
#pragma unroll
  for (int d = 0; d < F; d += 4) {
    float4 qv = *(const float4*)(qrow + d);
    float4 v0 = *(const float4*)(crow0 + d);
    float4 v1 = *(const float4*)(crow1 + d);
    dot0 += qv.x * v0.x + qv.y * v0.y + qv.z * v0.z + qv.w * v0.w;
    dot1 += qv.x * v1.x + qv.y * v1.y + qv.z * v1.z + qv.w * v1.w;
  }
  float s0 = sqn[c0] - 2.0f * dot0;
  float s1 = sqn[c1] - 2.0f * dot1;
  // rank by (score asc, index asc); quarters are disjoint -> no duplicates
  int rank0 = 0, rank1 = 0;
#pragma unroll 1
  for (int j = 0; j < 64; ++j) {
    float a0 = __shfl(s0, j); int i0 = __shfl(c0, j);
    float a1 = __shfl(s1, j); int i1 = __shfl(c1, j);
    rank0 += ((a0 < s0) || (a0 == s0 && i0 < c0)) + ((a1 < s0) || (a1 == s0 && i1 < c0));
    rank1 += ((a0 < s1) || (a0 == s1 && i0 < c1)) + ((a1 < s1) || (a1 == s1 && i1 < c1));
  }
  if (rank0 < KNN) out_idx[(size_t)q * KNN + rank0] = c0;
  if (rank1 < KNN) out_idx[(size_t)q * KNN + rank1] = c1;
}

// x1 = relu(pos @ W1 + b1) + bf16 hi/lo split + squared row norms.
__global__ __launch_bounds__(256) void mlp1_kernel(const float* __restrict__ pos,
                                                   const float* __restrict__ W1,
                                                   const float* __restrict__ b1,
                                                   float* __restrict__ x1,
                                                   ushort* __restrict__ xh,
                                                   ushort* __restrict__ xl,
                                                   float* __restrict__ sqn) {
  int i = blockIdx.x * 4 + (threadIdx.x >> 6);
  int o = threadIdx.x & 63;
  float p0 = pos[i * 3], p1 = pos[i * 3 + 1], p2 = pos[i * 3 + 2];
  float v = p0 * W1[o] + p1 * W1[64 + o] + p2 * W1[128 + o] + b1[o];
  v = fmaxf(v, 0.f);
  x1[(size_t)i * 64 + o] = v;
  __hip_bfloat16 h = __float2bfloat16(v);
  float hv = __bfloat162float(h);
  __hip_bfloat16 l2 = __float2bfloat16(v - hv);
  xh[(size_t)i * 64 + o] = *(ushort*)&h;
  xl[(size_t)i * 64 + o] = *(ushort*)&l2;
  float ss = v * v;
#pragma unroll
  for (int d = 32; d; d >>= 1) ss += __shfl_xor(ss, d);
  if (o == 0) sqn[i] = ss;
}

// Fused P = X@Wp + bias, Q = X@Wq (shared X staging). 4 rows x float4 each.
template<int K, int OUT>
__global__ __launch_bounds__(256) void linpq_kernel(const float* __restrict__ X,
                                                    const float* __restrict__ Wp,
                                                    const float* __restrict__ bp,
                                                    const float* __restrict__ Wq,
                                                    float* __restrict__ P,
                                                    float* __restrict__ Q) {
  constexpr int XD = OUT / 4;
  constexpr int YD = 256 / XD;
  constexpr int R = YD * 4;
  __shared__ float xs[R * K];
  const int tid = threadIdx.x;
  const int tx = tid % XD, ty = tid / XD;
  const size_t r0 = (size_t)blockIdx.x * R;
  const float4* Xv = (const float4*)(X + r0 * K);
  float4* xsv = (float4*)xs;
#pragma unroll
  for (int i2 = tid; i2 < R * K / 4; i2 += 256) xsv[i2] = Xv[i2];
  __syncthreads();
  float4 ap[4], aq[4];
#pragma unroll
  for (int i = 0; i < 4; i++) { ap[i] = make_float4(0,0,0,0); aq[i] = make_float4(0,0,0,0); }
  const float4* Wp4 = (const float4*)Wp;
  const float4* Wq4 = (const float4*)Wq;
#pragma unroll 4
  for (int k = 0; k < K; ++k) {
    float4 wp = Wp4[k * XD + tx];
    float4 wq = Wq4[k * XD + tx];
#pragma unroll
    for (int i = 0; i < 4; i++) {
      float xv = xs[(ty * 4 + i) * K + k];
      ap[i].x += xv * wp.x; ap[i].y += xv * wp.y; ap[i].z += xv * wp.z; ap[i].w += xv * wp.w;
      aq[i].x += xv * wq.x; aq[i].y += xv * wq.y; aq[i].z += xv * wq.z; aq[i].w += xv * wq.w;
    }
  }
  float4 bv = ((const float4*)bp)[tx];
#pragma unroll
  for (int i = 0; i < 4; i++) {
    float4 o;
    o.x = ap[i].x + bv.x; o.y = ap[i].y + bv.y; o.z = ap[i].z + bv.z; o.w = ap[i].w + bv.w;
    ((float4*)(P + (r0 + ty * 4 + i) * OUT))[tx] = o;
    ((float4*)(Q + (r0 + ty * 4 + i) * OUT))[tx] = aq[i];
  }
}

// Layer-1 epilogue fused: x2 = relu(P + max_j Q[nb]), plus hi/lo split + norms.
__global__ void maxpoolprep_kernel(const float* __restrict__ P, const float* __restrict__ Qm,
                                   const int* __restrict__ idx, float* __restrict__ xo,
                                   ushort* __restrict__ xh, ushort* __restrict__ xl,
                                   float* __restrict__ sqn) {
  __shared__ int nb[KNN];
  __shared__ float part[2];
  int i = blockIdx.x;
  if (threadIdx.x < KNN) nb[threadIdx.x] = idx[(size_t)i * KNN + threadIdx.x];
  __syncthreads();
  int o = threadIdx.x;  // 128 threads
  float m = -3.0e38f;
#pragma unroll
  for (int j = 0; j < KNN; j++) m = fmaxf(m, Qm[(size_t)nb[j] * 128 + o]);
  float v = fmaxf(P[(size_t)i * 128 + o] + m, 0.f);
  xo[(size_t)i * 128 + o] = v;
  __hip_bfloat16 h = __float2bfloat16(v);
  float hv = __bfloat162float(h);
  __hip_bfloat16 l2 = __float2bfloat16(v - hv);
  xh[(size_t)i * 128 + o] = *(ushort*)&h;
  xl[(size_t)i * 128 + o] = *(ushort*)&l2;
  float ss = v * v;
#pragma unroll
  for (int d = 32; d; d >>= 1) ss += __shfl_xor(ss, d);
  if ((threadIdx.x & 63) == 0) part[threadIdx.x >> 6] = ss;
  __syncthreads();
  if (threadIdx.x == 0) sqn[i] = part[0] + part[1];
}

// out_i = relu(P_i + max_j Q[idx[i][j]])
template<int OUT>
__global__ void maxpool_kernel(const float* __restrict__ P, const float* __restrict__ Q,
                               const int* __restrict__ idx, float* __restrict__ xo) {
  __shared__ int nb[KNN];
  int i = blockIdx.x;
  if (threadIdx.x < KNN) nb[threadIdx.x] = idx[(size_t)i * KNN + threadIdx.x];
  __syncthreads();
  int o = threadIdx.x;
  float m = -3.0e38f;
#pragma unroll
  for (int j = 0; j < KNN; j++) m = fmaxf(m, Q[(size_t)nb[j] * OUT + o]);
  float p = P[(size_t)i * OUT + o];
  xo[(size_t)i * OUT + o] = fmaxf(p + m, 0.f);
}

// C[N x OUT] = X[N x K] @ W[K x OUT] (+ bias). Register-tiled 4 rows x float4.
template<int K, int OUT, bool BIAS>
__global__ __launch_bounds__(256) void lin_kernel(const float* __restrict__ X,
                                                  const float* __restrict__ W,
                                                  const float* __restrict__ bias,
                                                  float* __restrict__ C) {
  constexpr int XD = OUT / 4;
  constexpr int YD = 256 / XD;
  constexpr int R = YD * 4;
  __shared__ float xs[R * K];
  const int tid = threadIdx.x;
  const int tx = tid % XD, ty = tid / XD;
  const size_t r0 = (size_t)blockIdx.x * R;
  const float4* Xv = (const float4*)(X + r0 * K);
  float4* xsv = (float4*)xs;
#pragma unroll
  for (int i2 = tid; i2 < R * K / 4; i2 += 256) xsv[i2] = Xv[i2];
  __syncthreads();
  float4 acc[4];
#pragma unroll
  for (int i = 0; i < 4; i++) acc[i] = make_float4(0.f, 0.f, 0.f, 0.f);
  const float4* W4 = (const float4*)W;
#pragma unroll 8
  for (int k = 0; k < K; ++k) {
    float4 wv = W4[k * XD + tx];
#pragma unroll
    for (int i = 0; i < 4; i++) {
      float xv = xs[(ty * 4 + i) * K + k];
      acc[i].x += xv * wv.x; acc[i].y += xv * wv.y;
      acc[i].z += xv * wv.z; acc[i].w += xv * wv.w;
    }
  }
  float4 bv = make_float4(0.f, 0.f, 0.f, 0.f);
  if (BIAS) bv = ((const float4*)bias)[tx];
#pragma unroll
  for (int i = 0; i < 4; i++) {
    float4 o;
    o.x = acc[i].x + bv.x; o.y = acc[i].y + bv.y;
    o.z = acc[i].z + bv.z; o.w = acc[i].w + bv.w;
    ((float4*)(C + (r0 + ty * 4 + i) * OUT))[tx] = o;
  }
}

// Wp[k][o] = We[k][o] - We[K+k][o]
__global__ void wsub_kernel(const float* __restrict__ We, float* __restrict__ Wp, int total) {
  int t = blockIdx.x * 256 + threadIdx.x;
  if (t < total) Wp[t] = We[t] - We[total + t];
}

extern "C" void kernel_launch(void* const* d_in, const int* in_sizes, int n_in,
                              void* d_out, int out_size, void* d_ws, size_t ws_size,
                              hipStream_t stream) {
  const float* pos = (const float*)d_in[0];
  const float* W1  = (const float*)d_in[1];
  const float* b1  = (const float*)d_in[2];
  const float* We1 = (const float*)d_in[3];
  const float* be1 = (const float*)d_in[4];
  const float* We2 = (const float*)d_in[5];
  const float* be2 = (const float*)d_in[6];
  const float* W2  = (const float*)d_in[7];
  const float* b2  = (const float*)d_in[8];
  float* out = (float*)d_out;

  const size_t N = N_PTS;
  float* ws  = (float*)d_ws;
  float* x1  = ws;               // N*64
  float* P1  = x1 + N * 64;      // N*128
  float* Q1  = P1 + N * 128;     // N*128
  float* x2  = Q1 + N * 128;     // N*128
  float* P2  = x2 + N * 128;     // N*256
  float* Q2  = P2 + N * 256;     // N*256
  float* x3  = Q2 + N * 256;     // N*256
  float* sqn = x3 + N * 256;     // N (x1 norms, then x2 norms)
  float* Wp1 = sqn + N;          // 64*128
  float* Wp2 = Wp1 + 64 * 128;   // 128*256
  int* idx1  = (int*)(Wp2 + 128 * 256);  // N*20
  int* idx2  = idx1 + N * KNN;           // N*20
  // cand aliases Q2's slot (N*128 ints <= N*256 floats): fully consumed by
  // refine before Q2 is written by linpq (same stream, program order).
  int* cand  = (int*)Q2;
  ushort* X1h = (ushort*)(idx2 + N * KNN);  // N*64
  ushort* X1l = X1h + N * 64;               // N*64
  ushort* X2h = X1l + N * 64;               // N*128
  ushort* X2l = X2h + N * 128;              // N*128
  size_t need = (size_t)((char*)(X2l + N * 128) - (char*)d_ws);
  if (ws_size < need) return;  // insufficient scratch -> visible failure

  wsub_kernel<<<(64 * 128 + 255) / 256, 256, 0, stream>>>(We1, Wp1, 64 * 128);
  wsub_kernel<<<(128 * 256 + 255) / 256, 256, 0, stream>>>(We2, Wp2, 128 * 256);

  mlp1_kernel<<<N / 4, 256, 0, stream>>>(pos, W1, b1, x1, X1h, X1l, sqn);
  knn_kernel<64><<<(N / 32) * NSPLIT, 64, 0, stream>>>(X1h, X1l, sqn, cand);   // 2048 blocks
  refine_kernel<64><<<N / 4, 256, 0, stream>>>(x1, sqn, cand, idx1);
  linpq_kernel<64, 128><<<N / 32, 256, 0, stream>>>(x1, Wp1, be1, We1 + 64 * 128, P1, Q1);
  maxpoolprep_kernel<<<N, 128, 0, stream>>>(P1, Q1, idx1, x2, X2h, X2l, sqn);

  knn_kernel<128><<<(N / 32) * NSPLIT, 64, 0, stream>>>(X2h, X2l, sqn, cand);  // 2048 blocks
  refine_kernel<128><<<N / 4, 256, 0, stream>>>(x2, sqn, cand, idx2);
  linpq_kernel<128, 256><<<N / 16, 256, 0, stream>>>(x2, Wp2, be2, We2 + 128 * 256, P2, Q2);
  maxpool_kernel<256><<<N, 256, 0, stream>>>(P2, Q2, idx2, x3);

  lin_kernel<256, 128, true ><<<N / 32, 256, 0, stream>>>(x3, W2, b2, out);
}